// Round 1
// baseline (681.054 us; speedup 1.0000x reference)
//
#include <hip/hip_runtime.h>
#include <hip/hip_bf16.h>
#include <math.h>

#define B_ 8
#define T_ 128
#define U1_ 33
#define D_ 512
#define V_ 4096
#define M_ (B_*T_*U1_)   /* 33792 */

#define BLANK_ 0
#define PAD_ 1

#define BM 128
#define BN 256
#define BK 32
#define NT_ (V_/BN)      /* 16 n-tiles */
#define LDA 40           /* BK + 8 pad: conflict-free b128 frag reads */
#define LDB 40

typedef __attribute__((ext_vector_type(8))) short s8_t;      // 8 bf16 (4 VGPRs)
typedef __attribute__((ext_vector_type(4))) float fvec4;     // MFMA acc
typedef __attribute__((ext_vector_type(4))) unsigned short usvec4;

static_assert(M_ % BM == 0, "M tiles");
static_assert(V_ % BN == 0, "N tiles");
static_assert(D_ % BK == 0, "K tiles");

__device__ __forceinline__ unsigned short f2bf(float f) {
    union { float f; unsigned u; } v; v.f = f;
    unsigned r = v.u + 0x7FFFu + ((v.u >> 16) & 1u);   // RNE (inputs finite)
    return (unsigned short)(r >> 16);
}

// ---------------------------------------------------------------------------
// Kernel 1: fused GEMM (x @ W^T + bias) -> per-(row, n-tile) sum of exp
// grid (M/BM=264, V/BN=16), block 256 (4 waves), wave tile 64x128
// ---------------------------------------------------------------------------
__global__ __launch_bounds__(256, 2)
void gemm_lse_partial(const float* __restrict__ x, const float* __restrict__ w,
                      const float* __restrict__ bias, float* __restrict__ partial)
{
    __shared__ __align__(16) unsigned short As[2][BM][LDA];
    __shared__ __align__(16) unsigned short Bs[2][BN][LDB];
    __shared__ float ps[BM];

    const int tid  = threadIdx.x;
    const int lane = tid & 63;
    const int wid  = tid >> 6;
    const int m0   = blockIdx.x * BM;
    const int n0   = blockIdx.y * BN;

    // staging map: A: 2 threads/row (16 floats each); B: 1 thread/col (32 floats)
    const int ra = tid >> 1;
    const int ha = (tid & 1) * 16;

    fvec4 argA[4], argB[8];
    fvec4 acc[4][8];
#pragma unroll
    for (int i = 0; i < 4; i++)
#pragma unroll
        for (int j = 0; j < 8; j++) acc[i][j] = (fvec4)0.0f;

    const int wrow = (wid >> 1) * 64;   // wave row offset within BM
    const int wcol = (wid & 1) * 128;   // wave col offset within BN
    const int m15  = lane & 15;
    const int quad = lane >> 4;

    auto load_regs = [&](int kk) {
        const float* pa = x + (size_t)(m0 + ra) * D_ + kk + ha;
#pragma unroll
        for (int j = 0; j < 4; j++) argA[j] = ((const fvec4*)pa)[j];
        const float* pb = w + (size_t)(n0 + tid) * D_ + kk;
#pragma unroll
        for (int j = 0; j < 8; j++) argB[j] = ((const fvec4*)pb)[j];
    };
    auto cvt_write = [&](int nb) {
#pragma unroll
        for (int j = 0; j < 4; j++) {
            usvec4 t = { f2bf(argA[j].x), f2bf(argA[j].y), f2bf(argA[j].z), f2bf(argA[j].w) };
            *(usvec4*)&As[nb][ra][ha + j*4] = t;
        }
#pragma unroll
        for (int j = 0; j < 8; j++) {
            usvec4 t = { f2bf(argB[j].x), f2bf(argB[j].y), f2bf(argB[j].z), f2bf(argB[j].w) };
            *(usvec4*)&Bs[nb][tid][j*4] = t;
        }
    };

    load_regs(0);
    cvt_write(0);
    __syncthreads();

    for (int ks = 0; ks < D_/BK; ks++) {
        const int cur = ks & 1;
        if (ks < D_/BK - 1) load_regs((ks + 1) * BK);

        s8_t af[4], bf[8];
#pragma unroll
        for (int mi = 0; mi < 4; mi++)
            af[mi] = *(const s8_t*)&As[cur][wrow + mi*16 + m15][quad*8];
#pragma unroll
        for (int ni = 0; ni < 8; ni++)
            bf[ni] = *(const s8_t*)&Bs[cur][wcol + ni*16 + m15][quad*8];
#pragma unroll
        for (int mi = 0; mi < 4; mi++)
#pragma unroll
            for (int ni = 0; ni < 8; ni++)
                acc[mi][ni] = __builtin_amdgcn_mfma_f32_16x16x32_bf16(
                                  af[mi], bf[ni], acc[mi][ni], 0, 0, 0);

        if (ks < D_/BK - 1) cvt_write(cur ^ 1);
        __syncthreads();
    }

    // epilogue: sum of exp(logit + bias) per row
    if (tid < BM) ps[tid] = 0.0f;
    __syncthreads();

    float bv[8];
#pragma unroll
    for (int ni = 0; ni < 8; ni++) bv[ni] = bias[n0 + wcol + ni*16 + m15];

#pragma unroll
    for (int mi = 0; mi < 4; mi++) {
#pragma unroll
        for (int r = 0; r < 4; r++) {
            float s = 0.0f;
#pragma unroll
            for (int ni = 0; ni < 8; ni++)
                s += __expf(acc[mi][ni][r] + bv[ni]);
            // reduce across the 16 lanes holding this row's columns
            s += __shfl_xor(s, 1, 64);
            s += __shfl_xor(s, 2, 64);
            s += __shfl_xor(s, 4, 64);
            s += __shfl_xor(s, 8, 64);
            if (m15 == 0)
                atomicAdd(&ps[wrow + mi*16 + quad*4 + r], s);
        }
    }
    __syncthreads();
    if (tid < BM)
        partial[(size_t)(m0 + tid) * NT_ + blockIdx.y] = ps[tid];
}

// ---------------------------------------------------------------------------
// Kernel 2: combine partials -> lse
// ---------------------------------------------------------------------------
__global__ void lse_combine(const float* __restrict__ partial, float* __restrict__ lse)
{
    int r = blockIdx.x * 256 + threadIdx.x;
    if (r < M_) {
        float s = 0.0f;
#pragma unroll
        for (int j = 0; j < NT_; j++) s += partial[(size_t)r * NT_ + j];
        lse[r] = __logf(s);
    }
}

// ---------------------------------------------------------------------------
// Kernel 3: blank & emit logits (one wave per row)
// ---------------------------------------------------------------------------
__global__ __launch_bounds__(256)
void blank_emit(const float* __restrict__ x, const float* __restrict__ w,
                const float* __restrict__ bias, const int* __restrict__ targets,
                float* __restrict__ blank_z, float* __restrict__ emit_z)
{
    int gw   = (blockIdx.x * 256 + threadIdx.x) >> 6;   // row
    int lane = threadIdx.x & 63;
    int u = gw % U1_;
    int b = gw / (T_ * U1_);
    int tgt = (u < U1_ - 1) ? targets[b*(U1_-1) + u] : 0;

    const fvec4* xr = (const fvec4*)(x + (size_t)gw * D_);
    const fvec4* w0 = (const fvec4*)(w + (size_t)BLANK_ * D_);
    const fvec4* wt = (const fvec4*)(w + (size_t)tgt * D_);
    float s0 = 0.0f, st = 0.0f;
#pragma unroll
    for (int j = 0; j < 2; j++) {
        fvec4 xv = xr[lane*2 + j];
        fvec4 a  = w0[lane*2 + j];
        fvec4 bb = wt[lane*2 + j];
        s0 += xv.x*a.x  + xv.y*a.y  + xv.z*a.z  + xv.w*a.w;
        st += xv.x*bb.x + xv.y*bb.y + xv.z*bb.z + xv.w*bb.w;
    }
#pragma unroll
    for (int off = 1; off < 64; off <<= 1) {
        s0 += __shfl_xor(s0, off, 64);
        st += __shfl_xor(st, off, 64);
    }
    if (lane == 0) {
        blank_z[gw] = s0 + bias[BLANK_];
        emit_z[gw]  = st + bias[tgt];
    }
}

// ---------------------------------------------------------------------------
// Kernel 4: w_sum[d] = sum_v W[v][d]; w_sum[512] = sum_v bias[v]
// grid 32 x 256 threads, atomicAdd into zeroed buffer
// ---------------------------------------------------------------------------
__global__ void wsum_kernel(const float* __restrict__ w, const float* __restrict__ bias,
                            float* __restrict__ w_sum)
{
    int t  = threadIdx.x;
    int v0 = blockIdx.x * 128;
    float s0 = 0.0f, s1 = 0.0f;
    for (int v = 0; v < 128; v++) {
        s0 += w[(size_t)(v0 + v) * D_ + t];
        s1 += w[(size_t)(v0 + v) * D_ + t + 256];
    }
    atomicAdd(&w_sum[t], s0);
    atomicAdd(&w_sum[t + 256], s1);
    if (t < 128) atomicAdd(&w_sum[512], bias[v0 + t]);
}

// ---------------------------------------------------------------------------
// Kernel 5: RNN-T forward DP, anti-diagonal wavefront, one wave per b
// ---------------------------------------------------------------------------
__global__ __launch_bounds__(512)
void dp_kernel(const float* __restrict__ blank_z, const float* __restrict__ emit_z,
               const float* __restrict__ lse, const int* __restrict__ src_lengths,
               const int* __restrict__ tgt_lengths, float* __restrict__ out)
{
    int b = threadIdx.x >> 6;
    int u = threadIdx.x & 63;
    int sl = src_lengths[b], tl = tgt_lengths[b];
    const int base = b * T_ * U1_;

    float prev = 0.0f;   // d=0: lane 0 holds alpha[0][0] = 0
    float afin = 0.0f;

    for (int d = 1; d <= (T_-1) + (U1_-1); d++) {
        int t = d - u;
        float up = __shfl_up(prev, 1, 64);   // alpha[t][u-1] from lane u-1
        bool valid = (u < U1_) && (t >= 0) && (t < T_);
        if (valid) {
            float val;
            if (t == 0) {
                int i = base + (u - 1);                    // emit[b][0][u-1]
                val = up + (emit_z[i] - lse[i]);
            } else if (u == 0) {
                int i = base + (t - 1) * U1_;              // blank[b][t-1][0]
                val = prev + (blank_z[i] - lse[i]);
            } else {
                int ib = base + (t - 1) * U1_ + u;         // blank[b][t-1][u]
                int ie = base + t * U1_ + (u - 1);         // emit[b][t][u-1]
                float a1 = prev + (blank_z[ib] - lse[ib]);
                float a2 = up   + (emit_z[ie]  - lse[ie]);
                float mx = fmaxf(a1, a2), mn = fminf(a1, a2);
                val = mx + log1pf(__expf(mn - mx));
            }
            prev = val;
            if (t == sl - 1 && u == tl) afin = val;
        }
    }
#pragma unroll
    for (int off = 1; off < 64; off <<= 1) afin += __shfl_xor(afin, off, 64);
    if (u == 0) {
        int i = base + (sl - 1) * U1_ + tl;
        float bfin = blank_z[i] - lse[i];
        atomicAdd(out, -(afin + bfin));
    }
}

// ---------------------------------------------------------------------------
// Kernel 6: label-smoothed CE at t = src_len-1 (one wave per (b,u))
// ---------------------------------------------------------------------------
__global__ __launch_bounds__(256)
void ce_kernel(const float* __restrict__ x, const int* __restrict__ targets,
               const int* __restrict__ src_lengths,
               const float* __restrict__ emit_z, const float* __restrict__ lse,
               const float* __restrict__ w_sum, float* __restrict__ out)
{
    int gw   = (blockIdx.x * 256 + threadIdx.x) >> 6;   // 0..255
    int lane = threadIdx.x & 63;
    int b = gw >> 5;
    int u = gw & 31;
    int sl  = src_lengths[b];
    int tgt = targets[b*(U1_-1) + u];
    int row = (b*T_ + sl - 1) * U1_ + u;

    const fvec4* xr  = (const fvec4*)(x + (size_t)row * D_);
    const fvec4* ws4 = (const fvec4*)w_sum;
    float s = 0.0f;
#pragma unroll
    for (int j = 0; j < 2; j++) {
        fvec4 xv = xr[lane*2 + j], wv = ws4[lane*2 + j];
        s += xv.x*wv.x + xv.y*wv.y + xv.z*wv.z + xv.w*wv.w;
    }
#pragma unroll
    for (int off = 1; off < 64; off <<= 1) s += __shfl_xor(s, off, 64);

    if (lane == 0 && tgt != PAD_) {
        float zsum = s + w_sum[512];              // sum_v logits
        float l = lse[row];
        float nll = l - emit_z[row];              // -log p(target)
        float smooth = (float)V_ * l - zsum;      // -sum_v log p(v)
        const float eps_i = 0.1f / (float)(V_ - 1);
        float contrib = (1.0f - 0.1f - eps_i) * nll + eps_i * smooth;
        atomicAdd(out, contrib);                  // CE_SCALE = 1
    }
}

// ---------------------------------------------------------------------------
extern "C" void kernel_launch(void* const* d_in, const int* in_sizes, int n_in,
                              void* d_out, int out_size, void* d_ws, size_t ws_size,
                              hipStream_t stream)
{
    const float* x           = (const float*)d_in[0];
    const float* w           = (const float*)d_in[1];
    const float* bias        = (const float*)d_in[2];
    const int*   targets     = (const int*)d_in[3];
    const int*   src_lengths = (const int*)d_in[4];
    const int*   tgt_lengths = (const int*)d_in[5];
    float* out = (float*)d_out;

    float* wsf     = (float*)d_ws;
    float* partial = wsf;                                  // M*NT
    float* lse     = partial + (size_t)M_ * NT_;           // M
    float* blank_z = lse + M_;                             // M
    float* emit_z  = blank_z + M_;                         // M
    float* w_sum   = emit_z + M_;                          // 513

    hipMemsetAsync(out, 0, sizeof(float), stream);
    hipMemsetAsync(w_sum, 0, 513 * sizeof(float), stream);

    gemm_lse_partial<<<dim3(M_/BM, V_/BN), 256, 0, stream>>>(x, w, bias, partial);
    lse_combine<<<M_/256, 256, 0, stream>>>(partial, lse);
    blank_emit<<<M_/4, 256, 0, stream>>>(x, w, bias, targets, blank_z, emit_z);
    wsum_kernel<<<32, 256, 0, stream>>>(w, bias, w_sum);
    dp_kernel<<<1, 512, 0, stream>>>(blank_z, emit_z, lse, src_lengths, tgt_lengths, out);
    ce_kernel<<<64, 256, 0, stream>>>(x, targets, src_lengths, emit_z, lse, w_sum, out);
}

// Round 2
// 394.787 us; speedup vs baseline: 1.7251x; 1.7251x over previous
//
#include <hip/hip_runtime.h>
#include <hip/hip_bf16.h>
#include <math.h>

#define B_ 8
#define T_ 128
#define U1_ 33
#define D_ 512
#define V_ 4096
#define M_ (B_*T_*U1_)   /* 33792 */

#define BLANK_ 0
#define PAD_ 1

#define TM 128           /* block M tile */
#define TN 128           /* block N tile */
#define BK 32            /* K step (bf16 elems) */
#define NK (D_/BK)       /* 16 */
#define GN (V_/TN)       /* 32 n-tiles */

typedef __attribute__((ext_vector_type(8))) short s8_t;      // 8 bf16 (4 VGPRs)
typedef __attribute__((ext_vector_type(4))) float fvec4;
typedef __attribute__((ext_vector_type(4))) unsigned short usvec4;
typedef unsigned short ushort_t;

__device__ __forceinline__ unsigned short f2bf(float f) {
    union { float f; unsigned u; } v; v.f = f;
    unsigned r = v.u + 0x7FFFu + ((v.u >> 16) & 1u);   // RNE (inputs finite)
    return (unsigned short)(r >> 16);
}

// async global->LDS, 16B per lane; LDS dest = wave-uniform base + lane*16
__device__ __forceinline__ void load_lds16(const ushort_t* g, ushort_t* l) {
    __builtin_amdgcn_global_load_lds(
        (const __attribute__((address_space(1))) unsigned int*)g,
        (__attribute__((address_space(3))) unsigned int*)l,
        16, 0, 0);
}

// ---------------------------------------------------------------------------
// Kernel 0: fp32 -> bf16 convert for x and w
// ---------------------------------------------------------------------------
__global__ void convert_kernel(const float* __restrict__ x, const float* __restrict__ w,
                               ushort_t* __restrict__ xbf, ushort_t* __restrict__ wbf)
{
    int i = blockIdx.x * 256 + threadIdx.x;
    int stride = gridDim.x * 256;
    const int nx = (M_ * D_) / 4;       // 4325376
    const int nw = (V_ * D_) / 4;       // 524288
    for (int j = i; j < nx; j += stride) {
        fvec4 v = ((const fvec4*)x)[j];
        usvec4 o = { f2bf(v.x), f2bf(v.y), f2bf(v.z), f2bf(v.w) };
        ((usvec4*)xbf)[j] = o;
    }
    for (int j = i; j < nw; j += stride) {
        fvec4 v = ((const fvec4*)w)[j];
        usvec4 o = { f2bf(v.x), f2bf(v.y), f2bf(v.z), f2bf(v.w) };
        ((usvec4*)wbf)[j] = o;
    }
}

// ---------------------------------------------------------------------------
// Kernel 1: m97-structure GEMM (xbf @ wbf^T + bias) with fused epilogue:
//   - per-(row, n-tile) sum of exp(logit)            -> partial (transposed)
//   - blank logit (col 0)                            -> blank_z
//   - target-column logit                            -> emit_z
// grid (M/128=264, V/128=32), block 256 (2x2 waves of 64x64)
// ---------------------------------------------------------------------------
__global__ __launch_bounds__(256, 3)
void gemm_fused(const ushort_t* __restrict__ xbf, const ushort_t* __restrict__ wbf,
                const float* __restrict__ bias, const int* __restrict__ targets,
                float* __restrict__ partial, float* __restrict__ blank_z,
                float* __restrict__ emit_z)
{
    // unpadded [row][k] layout, row stride 32 bf16 = 64 B (global_load_lds order)
    __shared__ __align__(16) ushort_t As[2][TM * BK];
    __shared__ __align__(16) ushort_t Bs[2][TN * BK];
    __shared__ float ps[TM];
    __shared__ int tgt_s[TM];

    const int tid  = threadIdx.x;
    const int lane = tid & 63;
    const int wid  = tid >> 6;
    const int m0   = blockIdx.x * TM;
    const int n0   = blockIdx.y * TN;

    // staging: lane i of wave w, issue j: row = j*64 + w*16 + (i>>2), kchunk = i&3
    const int srow  = wid * 16 + (lane >> 2);
    const int skcol = (lane & 3) * 8;
    const ushort_t* agp = xbf + (size_t)(m0 + srow) * D_ + skcol;
    const ushort_t* bgp = wbf + (size_t)(n0 + srow) * D_ + skcol;
    const int lbase = (wid * 16) * BK;   // wave-uniform LDS elem offset (issue 0)

    fvec4 acc[4][4];
#pragma unroll
    for (int i = 0; i < 4; i++)
#pragma unroll
        for (int j = 0; j < 4; j++) acc[i][j] = (fvec4)0.0f;

    const int wrow = (wid >> 1) * 64;
    const int wcol = (wid & 1) * 64;
    const int m15  = lane & 15;
    const int quad = lane >> 4;

    auto stage = [&](int buf, int ks) {
        const ushort_t* ag = agp + ks * BK;
        const ushort_t* bg = bgp + ks * BK;
        load_lds16(ag,            &As[buf][lbase]);
        load_lds16(ag + 64 * D_,  &As[buf][lbase + 64 * BK]);
        load_lds16(bg,            &Bs[buf][lbase]);
        load_lds16(bg + 64 * D_,  &Bs[buf][lbase + 64 * BK]);
    };

    stage(0, 0);
    __syncthreads();

    for (int ks = 0; ks < NK; ks++) {
        const int cur = ks & 1;
        if (ks + 1 < NK) stage(cur ^ 1, ks + 1);

        s8_t af[4], bf[4];
#pragma unroll
        for (int mi = 0; mi < 4; mi++)
            af[mi] = *(const s8_t*)&As[cur][(wrow + mi*16 + m15) * BK + quad * 8];
#pragma unroll
        for (int ni = 0; ni < 4; ni++)
            bf[ni] = *(const s8_t*)&Bs[cur][(wcol + ni*16 + m15) * BK + quad * 8];
#pragma unroll
        for (int mi = 0; mi < 4; mi++)
#pragma unroll
            for (int ni = 0; ni < 4; ni++)
                acc[mi][ni] = __builtin_amdgcn_mfma_f32_16x16x32_bf16(
                                  af[mi], bf[ni], acc[mi][ni], 0, 0, 0);
        __syncthreads();
    }

    // ---- epilogue ----
    if (tid < TM) {
        ps[tid] = 0.0f;
        int row = m0 + tid;
        int u = row % U1_;
        int b = row / (T_ * U1_);
        tgt_s[tid] = (u < U1_ - 1) ? targets[b * (U1_ - 1) + u] : -1;
    }
    __syncthreads();

    float bv[4];
#pragma unroll
    for (int ni = 0; ni < 4; ni++) bv[ni] = bias[n0 + wcol + ni*16 + m15];

    const bool blank_lane = (blockIdx.y == 0) && (wcol == 0) && (m15 == 0);

#pragma unroll
    for (int mi = 0; mi < 4; mi++) {
#pragma unroll
        for (int r = 0; r < 4; r++) {
            const int irow = wrow + mi*16 + quad*4 + r;   // row within block tile
            float s = 0.0f;
#pragma unroll
            for (int ni = 0; ni < 4; ni++) {
                float z = acc[mi][ni][r] + bv[ni];
                s += __expf(z);
                int c = n0 + wcol + ni*16 + m15;
                if (tgt_s[irow] == c) emit_z[m0 + irow] = z;
            }
            if (blank_lane) blank_z[m0 + irow] = acc[mi][0][r] + bv[0];
            s += __shfl_xor(s, 1, 64);
            s += __shfl_xor(s, 2, 64);
            s += __shfl_xor(s, 4, 64);
            s += __shfl_xor(s, 8, 64);
            if (m15 == 0) atomicAdd(&ps[irow], s);
        }
    }
    __syncthreads();
    if (tid < TM)
        partial[(size_t)blockIdx.y * M_ + m0 + tid] = ps[tid];   // transposed: coalesced both ways
}

// ---------------------------------------------------------------------------
// Kernel 2: combine partials -> lse; also blank_lp/emit_lp = z - lse
// ---------------------------------------------------------------------------
__global__ void lse_combine(const float* __restrict__ partial,
                            const float* __restrict__ blank_z, const float* __restrict__ emit_z,
                            float* __restrict__ lse, float* __restrict__ blank_lp,
                            float* __restrict__ emit_lp)
{
    int r = blockIdx.x * 256 + threadIdx.x;   // grid covers M_ exactly
    float s = 0.0f;
#pragma unroll
    for (int j = 0; j < GN; j++) s += partial[(size_t)j * M_ + r];
    float l = __logf(s);
    lse[r]      = l;
    blank_lp[r] = blank_z[r] - l;
    emit_lp[r]  = emit_z[r] - l;
}

// ---------------------------------------------------------------------------
// Kernel 3: w_sum[d] = sum_v W[v][d]; w_sum[512] = sum_v bias[v]
// ---------------------------------------------------------------------------
__global__ void wsum_kernel(const float* __restrict__ w, const float* __restrict__ bias,
                            float* __restrict__ w_sum)
{
    int t  = threadIdx.x;
    int v0 = blockIdx.x * 128;
    float s0 = 0.0f, s1 = 0.0f;
    for (int v = 0; v < 128; v++) {
        s0 += w[(size_t)(v0 + v) * D_ + t];
        s1 += w[(size_t)(v0 + v) * D_ + t + 256];
    }
    atomicAdd(&w_sum[t], s0);
    atomicAdd(&w_sum[t + 256], s1);
    if (t < 128) atomicAdd(&w_sum[512], bias[v0 + t]);
}

// ---------------------------------------------------------------------------
// Kernel 4: RNN-T forward DP from LDS, one block per utterance
// ---------------------------------------------------------------------------
__global__ __launch_bounds__(256)
void dp_kernel(const float* __restrict__ blank_lp, const float* __restrict__ emit_lp,
               const int* __restrict__ src_lengths, const int* __restrict__ tgt_lengths,
               float* __restrict__ out)
{
    __shared__ float blp[T_ * U1_];
    __shared__ float elp[T_ * U1_];
    const int tid = threadIdx.x;
    const int b = blockIdx.x;
    for (int i = tid; i < T_ * U1_; i += 256) {
        blp[i] = blank_lp[b * T_ * U1_ + i];
        elp[i] = emit_lp[b * T_ * U1_ + i];
    }
    __syncthreads();
    if (tid >= 64) return;

    const int u = tid;
    const int sl = src_lengths[b], tl = tgt_lengths[b];

    float val = 0.0f;    // alpha along this lane's u-column
    float afin = 0.0f;

    for (int d = 1; d <= (T_ - 1) + (U1_ - 1); d++) {
        int t = d - u;
        float up = __shfl_up(val, 1, 64);
        bool valid = (u < U1_) && (t >= 0) && (t < T_);
        if (valid) {
            if (t == 0) {
                val = up + elp[u - 1];
            } else if (u == 0) {
                val = val + blp[(t - 1) * U1_];
            } else {
                float a1 = val + blp[(t - 1) * U1_ + u];
                float a2 = up  + elp[t * U1_ + (u - 1)];
                float mx = fmaxf(a1, a2), mn = fminf(a1, a2);
                val = mx + log1pf(__expf(mn - mx));
            }
            if (t == sl - 1 && u == tl) afin = val;
        }
    }
#pragma unroll
    for (int off = 1; off < 64; off <<= 1) afin += __shfl_xor(afin, off, 64);
    if (u == 0) {
        float bfin = blp[(sl - 1) * U1_ + tl];
        atomicAdd(out, -(afin + bfin));
    }
}

// ---------------------------------------------------------------------------
// Kernel 5: label-smoothed CE at t = src_len-1 (one wave per (b,u))
// ---------------------------------------------------------------------------
__global__ __launch_bounds__(256)
void ce_kernel(const float* __restrict__ x, const int* __restrict__ targets,
               const int* __restrict__ src_lengths,
               const float* __restrict__ emit_z, const float* __restrict__ lse,
               const float* __restrict__ w_sum, float* __restrict__ out)
{
    int gw   = (blockIdx.x * 256 + threadIdx.x) >> 6;   // 0..255
    int lane = threadIdx.x & 63;
    int b = gw >> 5;
    int u = gw & 31;
    int sl  = src_lengths[b];
    int tgt = targets[b * (U1_ - 1) + u];
    int row = (b * T_ + sl - 1) * U1_ + u;

    const fvec4* xr  = (const fvec4*)(x + (size_t)row * D_);
    const fvec4* ws4 = (const fvec4*)w_sum;
    float s = 0.0f;
#pragma unroll
    for (int j = 0; j < 2; j++) {
        fvec4 xv = xr[lane * 2 + j], wv = ws4[lane * 2 + j];
        s += xv.x * wv.x + xv.y * wv.y + xv.z * wv.z + xv.w * wv.w;
    }
#pragma unroll
    for (int off = 1; off < 64; off <<= 1) s += __shfl_xor(s, off, 64);

    if (lane == 0 && tgt != PAD_) {
        float zsum = s + w_sum[512];
        float l = lse[row];
        float nll = l - emit_z[row];
        float smooth = (float)V_ * l - zsum;
        const float eps_i = 0.1f / (float)(V_ - 1);
        float contrib = (1.0f - 0.1f - eps_i) * nll + eps_i * smooth;
        atomicAdd(out, contrib);
    }
}

// ---------------------------------------------------------------------------
extern "C" void kernel_launch(void* const* d_in, const int* in_sizes, int n_in,
                              void* d_out, int out_size, void* d_ws, size_t ws_size,
                              hipStream_t stream)
{
    const float* x           = (const float*)d_in[0];
    const float* w           = (const float*)d_in[1];
    const float* bias        = (const float*)d_in[2];
    const int*   targets     = (const int*)d_in[3];
    const int*   src_lengths = (const int*)d_in[4];
    const int*   tgt_lengths = (const int*)d_in[5];
    float* out = (float*)d_out;

    // workspace carve (bytes): xbf 34.6MB | wbf 4.2MB | partial 4.3MB | 6 small
    char* p = (char*)d_ws;
    ushort_t* xbf = (ushort_t*)p;              p += (size_t)M_ * D_ * sizeof(ushort_t);
    ushort_t* wbf = (ushort_t*)p;              p += (size_t)V_ * D_ * sizeof(ushort_t);
    float* partial  = (float*)p;               p += (size_t)GN * M_ * sizeof(float);
    float* lse      = (float*)p;               p += (size_t)M_ * sizeof(float);
    float* blank_z  = (float*)p;               p += (size_t)M_ * sizeof(float);
    float* emit_z   = (float*)p;               p += (size_t)M_ * sizeof(float);
    float* blank_lp = (float*)p;               p += (size_t)M_ * sizeof(float);
    float* emit_lp  = (float*)p;               p += (size_t)M_ * sizeof(float);
    float* w_sum    = (float*)p;               p += 513 * sizeof(float);

    hipMemsetAsync(out, 0, sizeof(float), stream);
    hipMemsetAsync(w_sum, 0, 513 * sizeof(float), stream);

    convert_kernel<<<4096, 256, 0, stream>>>(x, w, xbf, wbf);
    gemm_fused<<<dim3(M_/TM, V_/TN), 256, 0, stream>>>(xbf, wbf, bias, targets,
                                                       partial, blank_z, emit_z);
    lse_combine<<<M_/256, 256, 0, stream>>>(partial, blank_z, emit_z, lse, blank_lp, emit_lp);
    wsum_kernel<<<32, 256, 0, stream>>>(w, bias, w_sum);
    dp_kernel<<<B_, 256, 0, stream>>>(blank_lp, emit_lp, src_lengths, tgt_lengths, out);
    ce_kernel<<<64, 256, 0, stream>>>(x, targets, src_lengths, emit_z, lse, w_sum, out);
}

// Round 3
// 364.703 us; speedup vs baseline: 1.8674x; 1.0825x over previous
//
#include <hip/hip_runtime.h>
#include <hip/hip_bf16.h>
#include <math.h>
#include <stdint.h>

#define B_ 8
#define T_ 128
#define U1_ 33
#define D_ 512
#define V_ 4096
#define M_ (B_*T_*U1_)   /* 33792 */

#define BLANK_ 0
#define PAD_ 1

#define TM 128           /* block M tile */
#define TN 128           /* block N tile */
#define BKB 128          /* K step in fp8 bytes (= MFMA K) */
#define NK (D_/BKB)      /* 4 */
#define GN (V_/TN)       /* 32 n-tiles */

typedef __attribute__((ext_vector_type(4))) float fvec4;
typedef __attribute__((ext_vector_type(8))) int   i8v;    // 32 fp8 = 8 VGPRs
typedef __attribute__((ext_vector_type(4))) int   i4v;

// E8M0 block scales: A x1 (2^0=bias127), B x2^-6 (121) to undo the x64 pre-scale
#define SCALE_A 0x7F7F7F7Fu
#define SCALE_B 0x79797979u

__device__ __forceinline__ void load_lds16(const uint8_t* g, uint8_t* l) {
    __builtin_amdgcn_global_load_lds(
        (const __attribute__((address_space(1))) unsigned int*)g,
        (__attribute__((address_space(3))) unsigned int*)l, 16, 0, 0);
}

__device__ __forceinline__ unsigned pack4_fp8(fvec4 v) {
    int r = __builtin_amdgcn_cvt_pk_fp8_f32(v.x, v.y, 0, false);
    r = __builtin_amdgcn_cvt_pk_fp8_f32(v.z, v.w, r, true);
    return (unsigned)r;
}

// ---------------------------------------------------------------------------
// Kernel 0: fp32 -> fp8 e4m3 convert; w is pre-scaled by 64 (undone by SCALE_B)
// ---------------------------------------------------------------------------
__global__ void convert_kernel(const float* __restrict__ x, const float* __restrict__ w,
                               uint8_t* __restrict__ xf8, uint8_t* __restrict__ wf8)
{
    int i = blockIdx.x * 256 + threadIdx.x;
    int stride = gridDim.x * 256;
    const int nx = (M_ * D_) / 16;   // 1081344 16B-groups
    const int nw = (V_ * D_) / 16;   // 131072
    for (int j = i; j < nx; j += stride) {
        const fvec4* p = (const fvec4*)x + (size_t)j * 4;
        uint4 o = { pack4_fp8(p[0]), pack4_fp8(p[1]), pack4_fp8(p[2]), pack4_fp8(p[3]) };
        ((uint4*)xf8)[j] = o;
    }
    for (int j = i; j < nw; j += stride) {
        const fvec4* p = (const fvec4*)w + (size_t)j * 4;
        fvec4 v0 = p[0]*64.0f, v1 = p[1]*64.0f, v2 = p[2]*64.0f, v3 = p[3]*64.0f;
        uint4 o = { pack4_fp8(v0), pack4_fp8(v1), pack4_fp8(v2), pack4_fp8(v3) };
        ((uint4*)wf8)[j] = o;
    }
}

// ---------------------------------------------------------------------------
// Kernel 1: MX-fp8 GEMM (x @ W^T + bias), 16x16x128 f8f6f4 scaled MFMA.
// Epilogue: per-(row,n-tile) sum(exp(z)) and sum(z); blank & target logits.
// LDS staging XOR-swizzled so frag ds_read_b128 covers all 32 banks.
// grid (264, 32), block 256 (2x2 waves of 64x64)
// ---------------------------------------------------------------------------
__global__ __launch_bounds__(256, 2)
void gemm_fused(const uint8_t* __restrict__ xf8, const uint8_t* __restrict__ wf8,
                const float* __restrict__ bias, const int* __restrict__ targets,
                float* __restrict__ partial_e, float* __restrict__ partial_z,
                float* __restrict__ blank_z, float* __restrict__ emit_z)
{
    __shared__ __align__(16) uint8_t As[2][TM * BKB];   // 16 KB x2
    __shared__ __align__(16) uint8_t Bs[2][TN * BKB];   // 16 KB x2
    __shared__ float ps[TM], pz[TM];
    __shared__ int tgt_s[TM];

    const int tid  = threadIdx.x;
    const int lane = tid & 63;
    const int wid  = tid >> 6;
    const int m0   = blockIdx.x * TM;
    const int n0   = blockIdx.y * TN;

    // staging: lane i -> LDS (row = wid*32 + j*8 + (i>>3), chunk = i&7);
    // global src chunk is XOR-swizzled by row&7
    const int srow = wid * 32 + (lane >> 3);
    const int schk = (lane & 7) ^ ((lane >> 3) & 7);
    const uint8_t* agp = xf8 + (size_t)(m0 + srow) * D_ + schk * 16;
    const uint8_t* bgp = wf8 + (size_t)(n0 + srow) * D_ + schk * 16;

    fvec4 acc[4][4];
#pragma unroll
    for (int i = 0; i < 4; i++)
#pragma unroll
        for (int j = 0; j < 4; j++) acc[i][j] = (fvec4)0.0f;

    const int wrow = (wid >> 1) * 64;
    const int wcol = (wid & 1) * 64;
    const int m15  = lane & 15;
    const int quad = lane >> 4;

    auto stage = [&](int buf, int ks) {
        const uint8_t* ag = agp + ks * BKB;
        const uint8_t* bg = bgp + ks * BKB;
#pragma unroll
        for (int j = 0; j < 4; j++) {
            load_lds16(ag + j * 8 * D_, &As[buf][(wid * 32 + j * 8) * BKB]);
            load_lds16(bg + j * 8 * D_, &Bs[buf][(wid * 32 + j * 8) * BKB]);
        }
    };

    stage(0, 0);
    __syncthreads();

    const int e   = m15 & 7;               // row&7 for all frag rows
    const int c0b = (((quad << 1) ^ e) << 4);   // first 16B chunk byte offset

    for (int ks = 0; ks < NK; ks++) {
        const int cur = ks & 1;
        if (ks + 1 < NK) stage(cur ^ 1, ks + 1);

        i8v fa[4], fb[4];
#pragma unroll
        for (int mi = 0; mi < 4; mi++) {
            int base = (wrow + mi * 16 + m15) << 7;   // row*128
            union { i4v h[2]; i8v w; } u;
            u.h[0] = *(const i4v*)&As[cur][base + c0b];
            u.h[1] = *(const i4v*)&As[cur][base + (c0b ^ 16)];
            fa[mi] = u.w;
        }
#pragma unroll
        for (int ni = 0; ni < 4; ni++) {
            int base = (wcol + ni * 16 + m15) << 7;
            union { i4v h[2]; i8v w; } u;
            u.h[0] = *(const i4v*)&Bs[cur][base + c0b];
            u.h[1] = *(const i4v*)&Bs[cur][base + (c0b ^ 16)];
            fb[ni] = u.w;
        }
#pragma unroll
        for (int mi = 0; mi < 4; mi++)
#pragma unroll
            for (int ni = 0; ni < 4; ni++)
                acc[mi][ni] = __builtin_amdgcn_mfma_scale_f32_16x16x128_f8f6f4(
                                  fa[mi], fb[ni], acc[mi][ni],
                                  0, 0,                 // fmtA=fp8, fmtB=fp8
                                  0, SCALE_A, 0, SCALE_B);
        __syncthreads();
    }

    // ---- epilogue ----
    if (tid < TM) {
        ps[tid] = 0.0f; pz[tid] = 0.0f;
        int row = m0 + tid;
        int u = row % U1_;
        int b = row / (T_ * U1_);
        tgt_s[tid] = (u < U1_ - 1) ? targets[b * (U1_ - 1) + u] : -1;
    }
    __syncthreads();

    float bv[4];
#pragma unroll
    for (int ni = 0; ni < 4; ni++) bv[ni] = bias[n0 + wcol + ni * 16 + m15];

    const bool blank_lane = (blockIdx.y == 0) && (wcol == 0) && (m15 == 0);

#pragma unroll
    for (int mi = 0; mi < 4; mi++) {
#pragma unroll
        for (int r = 0; r < 4; r++) {
            const int irow = wrow + mi * 16 + quad * 4 + r;
            float se = 0.0f, sz = 0.0f;
#pragma unroll
            for (int ni = 0; ni < 4; ni++) {
                float z = acc[mi][ni][r] + bv[ni];
                se += __expf(z);
                sz += z;
                int c = n0 + wcol + ni * 16 + m15;
                if (tgt_s[irow] == c) emit_z[m0 + irow] = z;
            }
            if (blank_lane) blank_z[m0 + irow] = acc[mi][0][r] + bv[0];
            se += __shfl_xor(se, 1, 64); sz += __shfl_xor(sz, 1, 64);
            se += __shfl_xor(se, 2, 64); sz += __shfl_xor(sz, 2, 64);
            se += __shfl_xor(se, 4, 64); sz += __shfl_xor(sz, 4, 64);
            se += __shfl_xor(se, 8, 64); sz += __shfl_xor(sz, 8, 64);
            if (m15 == 0) { atomicAdd(&ps[irow], se); atomicAdd(&pz[irow], sz); }
        }
    }
    __syncthreads();
    if (tid < TM) {
        partial_e[(size_t)blockIdx.y * M_ + m0 + tid] = ps[tid];
        partial_z[(size_t)blockIdx.y * M_ + m0 + tid] = pz[tid];
    }
}

// ---------------------------------------------------------------------------
// Kernel 2: combine partials -> lse; fused label-smoothed CE contribution
// ---------------------------------------------------------------------------
__global__ void lse_combine(const float* __restrict__ partial_e, const float* __restrict__ partial_z,
                            const float* __restrict__ emit_z, const int* __restrict__ targets,
                            const int* __restrict__ src_lengths,
                            float* __restrict__ lse, float* __restrict__ out)
{
    int r = blockIdx.x * 256 + threadIdx.x;   // grid covers M_ exactly
    float se = 0.0f, sz = 0.0f;
#pragma unroll
    for (int j = 0; j < GN; j++) {
        se += partial_e[(size_t)j * M_ + r];
        sz += partial_z[(size_t)j * M_ + r];
    }
    float l = __logf(se);
    lse[r] = l;

    // CE: rows with t == src_len-1, u < U1-1, target != PAD
    int b   = r / (T_ * U1_);
    int rem = r % (T_ * U1_);
    int t   = rem / U1_;
    int u   = rem % U1_;
    if (u < U1_ - 1 && t == src_lengths[b] - 1) {
        int tgt = targets[b * (U1_ - 1) + u];
        if (tgt != PAD_) {
            float nll    = l - emit_z[r];
            float smooth = (float)V_ * l - sz;
            const float eps_i = 0.1f / (float)(V_ - 1);
            atomicAdd(out, (1.0f - 0.1f - eps_i) * nll + eps_i * smooth);
        }
    }
}

// ---------------------------------------------------------------------------
// Kernel 3: RNN-T forward DP from LDS, one block per utterance
// ---------------------------------------------------------------------------
__global__ __launch_bounds__(256)
void dp_kernel(const float* __restrict__ blank_z, const float* __restrict__ emit_z,
               const float* __restrict__ lse, const int* __restrict__ src_lengths,
               const int* __restrict__ tgt_lengths, float* __restrict__ out)
{
    __shared__ float blp[T_ * U1_];
    __shared__ float elp[T_ * U1_];
    const int tid = threadIdx.x;
    const int b = blockIdx.x;
    for (int i = tid; i < T_ * U1_; i += 256) {
        int g = b * T_ * U1_ + i;
        float l = lse[g];
        blp[i] = blank_z[g] - l;
        elp[i] = emit_z[g] - l;
    }
    __syncthreads();
    if (tid >= 64) return;

    const int u = tid;
    const int ua = (u < U1_) ? u : U1_ - 1;
    const int sl = src_lengths[b], tl = tgt_lengths[b];

    float val = 0.0f;
    float afin = 0.0f;

    for (int d = 1; d <= (T_ - 1) + (U1_ - 1); d++) {
        int t = d - u;
        // unconditional clamped loads: keep LDS latency off the shfl chain
        int tb = t - 1; tb = tb < 0 ? 0 : (tb > T_ - 1 ? T_ - 1 : tb);
        int tc = t < 0 ? 0 : (t > T_ - 1 ? T_ - 1 : t);
        float blv = blp[tb * U1_ + ua];
        float elv = elp[tc * U1_ + (ua > 0 ? ua - 1 : 0)];
        float up = __shfl_up(val, 1, 64);
        bool valid = (u < U1_) && (t >= 0) && (t < T_);
        if (valid) {
            if (t == 0) {
                val = up + elv;
            } else if (u == 0) {
                val = val + blv;
            } else {
                float a1 = val + blv;
                float a2 = up + elv;
                float mx = fmaxf(a1, a2), mn = fminf(a1, a2);
                val = mx + log1pf(__expf(mn - mx));
            }
            if (t == sl - 1 && u == tl) afin = val;
        }
    }
#pragma unroll
    for (int off = 1; off < 64; off <<= 1) afin += __shfl_xor(afin, off, 64);
    if (u == 0) {
        float bfin = blp[(sl - 1) * U1_ + tl];
        atomicAdd(out, -(afin + bfin));
    }
}

// ---------------------------------------------------------------------------
extern "C" void kernel_launch(void* const* d_in, const int* in_sizes, int n_in,
                              void* d_out, int out_size, void* d_ws, size_t ws_size,
                              hipStream_t stream)
{
    const float* x           = (const float*)d_in[0];
    const float* w           = (const float*)d_in[1];
    const float* bias        = (const float*)d_in[2];
    const int*   targets     = (const int*)d_in[3];
    const int*   src_lengths = (const int*)d_in[4];
    const int*   tgt_lengths = (const int*)d_in[5];
    float* out = (float*)d_out;

    char* p = (char*)d_ws;
    uint8_t* xf8 = (uint8_t*)p;     p += (size_t)M_ * D_;                 // 17.3 MB
    uint8_t* wf8 = (uint8_t*)p;     p += (size_t)V_ * D_;                 //  2.1 MB
    float* partial_e = (float*)p;   p += (size_t)GN * M_ * sizeof(float); //  4.3 MB
    float* partial_z = (float*)p;   p += (size_t)GN * M_ * sizeof(float); //  4.3 MB
    float* lse       = (float*)p;   p += (size_t)M_ * sizeof(float);
    float* blank_z   = (float*)p;   p += (size_t)M_ * sizeof(float);
    float* emit_z    = (float*)p;   p += (size_t)M_ * sizeof(float);

    hipMemsetAsync(out, 0, sizeof(float), stream);

    convert_kernel<<<1536, 256, 0, stream>>>(x, w, xf8, wf8);
    gemm_fused<<<dim3(M_/TM, V_/TN), 256, 0, stream>>>(xf8, wf8, bias, targets,
                                                       partial_e, partial_z, blank_z, emit_z);
    lse_combine<<<M_/256, 256, 0, stream>>>(partial_e, partial_z, emit_z, targets,
                                            src_lengths, lse, out);
    dp_kernel<<<B_, 256, 0, stream>>>(blank_z, emit_z, lse, src_lengths, tgt_lengths, out);
}